// Round 1
// baseline (133.831 us; speedup 1.0000x reference)
//
#include <hip/hip_runtime.h>

// Problem constants (from reference)
#define TOTAL_WORDS 10000
#define EMB 100
#define SEQ 80
#define UNITS 64
#define BATCH 16384

// ---------------------------------------------------------------------------
// R15: occupancy attack on the rnn kernel. Counters showed the recurrence is
// latency-bound: MfmaUtil 23 / VALUBusy 29 / Occupancy 18% with the grid
// capped at 1024 blocks x 2 waves = 2 waves/SIMD. This round splits M=64
// across FOUR waves of M=16 each (same 16-row group per block, 256 threads):
//  - 6 MFMAs/wave/step instead of 12; weight frags per wave 6 -> lower VGPR
//  - 4096 total waves = 4 waves/SIMD = 4 independent recurrence chains/SIMD
//  - identical LDS exchange structure (hbuf + 2 lds_barriers per step), and
//    bit-identical per-unit accumulation order -> absmax unchanged
// prep_kernel is R14-verbatim (not in top-5 dispatches; gap is harness floor).
// ---------------------------------------------------------------------------

typedef _Float16 f16x4 __attribute__((ext_vector_type(4)));
typedef _Float16 f16x8 __attribute__((ext_vector_type(8)));
typedef _Float16 h2    __attribute__((ext_vector_type(2)));
typedef __fp16   fp16x2r __attribute__((ext_vector_type(2)));  // cvt_pkrtz ret
typedef float    f32x4 __attribute__((ext_vector_type(4)));

__device__ __forceinline__ h2 pkcvt(float a, float b) {
    fp16x2r t = __builtin_amdgcn_cvt_pkrtz(a, b);
    h2 o; o[0] = (_Float16)t[0]; o[1] = (_Float16)t[1];
    return o;
}

__device__ __forceinline__ h2 tanh_h2(h2 x) {
    // odd deg-5 in packed f16: |x| <= ~0.3 -> added err ~2e-4
    const _Float16 c3 = (_Float16)(-0.33333333f);
    const _Float16 c5 = (_Float16)(0.13333333f);
    h2 x2 = x * x;
    h2 p  = x2 * c5 + c3;     // v_pk_fma_f16
    h2 x3 = x2 * x;
    return x3 * p + x;        // v_pk_fma_f16
}

__device__ __forceinline__ f16x4 tanh_pack(f32x4 a) {
    h2 lo = tanh_h2(pkcvt(a[0], a[1]));
    h2 hi = tanh_h2(pkcvt(a[2], a[3]));
    f16x4 o;
    o[0] = lo[0]; o[1] = lo[1]; o[2] = hi[0]; o[3] = hi[1];
    return o;
}

// LDS-only barrier: drains ds ops, leaves global loads in flight.
__device__ __forceinline__ void lds_barrier() {
    asm volatile("s_waitcnt lgkmcnt(0)\n\ts_barrier" ::: "memory");
}

// ------------------- fused prologue: embW + weight packing -----------------
// blocks [0,250): embW rows [b*40, b*40+40). Wx0 staged once; each thread
//   owns (u = l, 10 consecutive v of its wave) with compile-time acc[10].
// blocks [250,298): pack K=32 A-frags for Wh0 / Wx1 / Wh1 (8 frags each,
//   512 f16 per frag). Frag(mat, f=mt*2+kf) elem (lane l, j<8) =
//   W[kf*32 + (l>>4)*8 + j][mt*16 + (l&15)]
__global__ void prep_kernel(const float* __restrict__ emb,
                            const float* __restrict__ Wx0,
                            const float* __restrict__ b0,
                            const float* __restrict__ Wh0,
                            const float* __restrict__ Wx1,
                            const float* __restrict__ Wh1,
                            float* __restrict__ embW,
                            _Float16* __restrict__ wfrags) {
    int b = blockIdx.x;
    if (b < 250) {
        __shared__ float wx[EMB * UNITS];  // 25.6 KB
        for (int i = threadIdx.x; i < EMB * UNITS; i += 256)
            wx[i] = Wx0[i];
        __syncthreads();
        const int u = threadIdx.x & 63;
        const int wvi = threadIdx.x >> 6;            // wave-uniform
        const int vbase = b * 40 + wvi * 10;         // wave-uniform
        const float bias = b0[u];
        float acc[10];
#pragma unroll
        for (int i = 0; i < 10; ++i) acc[i] = bias;
        const float* er = emb + vbase * EMB;         // wave-uniform base
#pragma unroll 4
        for (int k = 0; k < EMB; ++k) {
            float wxv = wx[k * UNITS + u];
#pragma unroll
            for (int i = 0; i < 10; ++i)
                acc[i] = fmaf(er[i * EMB + k], wxv, acc[i]);
        }
#pragma unroll
        for (int i = 0; i < 10; ++i)
            embW[(vbase + i) * UNITS + u] = acc[i];
    } else {
        int e = (b - 250) * 256 + threadIdx.x;       // 0..12287
        int mat = e >> 12;                           // 0: Wh0, 1: Wx1, 2: Wh1
        int ee = e & 4095;
        int f = ee >> 9;                             // frag 0..7
        int mt = f >> 1, kf = f & 1;
        int rr = ee & 511;
        int l = rr >> 3, j = rr & 7;
        int k = kf * 32 + (l >> 4) * 8 + j;
        int col = mt * 16 + (l & 15);
        const float* W = (mat == 0) ? Wh0 : (mat == 1) ? Wx1 : Wh1;
        wfrags[e] = (_Float16)W[k * UNITS + col];
    }
}

// ------------------------------ main kernel --------------------------------
// One timestep. E: this step's in-place embW slot (consumed as C-init,
// reloaded for t+4). T4: token for t+4 (compile-time int4 component).
// Wave w owns units [16w, 16w+16): one M-tile, 2 K-frags per matmul.
#define RNN_STEP(E, T4)                                                       \
    {                                                                         \
        f32x4 a = E;                       /* layer-0 C-init (b0 folded) */   \
        f32x4 c = b1v;                     /* layer-1 C-init (b1) */          \
        a = __builtin_amdgcn_mfma_f32_16x16x32_f16(w0[0], h0f0, a, 0, 0, 0);  \
        c = __builtin_amdgcn_mfma_f32_16x16x32_f16(wh[0], h1f0, c, 0, 0, 0);  \
        a = __builtin_amdgcn_mfma_f32_16x16x32_f16(w0[1], h0f1, a, 0, 0, 0);  \
        c = __builtin_amdgcn_mfma_f32_16x16x32_f16(wh[1], h1f1, c, 0, 0, 0);  \
        E = embWv[(T4) * 16 + w * 4 + q];             /* reload for t+4 */    \
        {                                                                     \
            f16x4 n0 = tanh_pack(a);                                          \
            *(uint2*)&hbuf0[r][16 * w + 4 * q] = *(const uint2*)&n0;          \
        }                                                                     \
        lds_barrier();                                                        \
        h0f0 = *(const f16x8*)&hbuf0[r][8 * q];                               \
        h0f1 = *(const f16x8*)&hbuf0[r][32 + 8 * q];                          \
        c = __builtin_amdgcn_mfma_f32_16x16x32_f16(wx[0], h0f0, c, 0, 0, 0);  \
        c = __builtin_amdgcn_mfma_f32_16x16x32_f16(wx[1], h0f1, c, 0, 0, 0);  \
        {                                                                     \
            f16x4 n1 = tanh_pack(c);                                          \
            *(uint2*)&hbuf1[r][16 * w + 4 * q] = *(const uint2*)&n1;          \
        }                                                                     \
        lds_barrier();                                                        \
        h1f0 = *(const f16x8*)&hbuf1[r][8 * q];                               \
        h1f1 = *(const f16x8*)&hbuf1[r][32 + 8 * q];                          \
    }

__global__ __launch_bounds__(256, 4) void rnn_mfma_kernel(
    const int*      __restrict__ tokens,   // [BATCH][SEQ]
    const float*    __restrict__ embW,     // [TOTAL_WORDS][UNITS]
    const _Float16* __restrict__ wfrags,   // packed f16 K=32 A-frags
    const float*    __restrict__ b1,       // [UNITS]
    const float*    __restrict__ Wout,     // [UNITS]
    const float*    __restrict__ bout,     // [1]
    float*          __restrict__ out) {    // [BATCH]
    const int tid = threadIdx.x;
    const int w   = tid >> 6;      // wave 0..3: owns units [16w, 16w+16)
    const int l   = tid & 63;
    const int r   = l & 15;        // batch row within the block's 16-row group
    const int q   = l >> 4;        // quad 0..3
    const int row0 = blockIdx.x * 16;

    // h-state buffers, stride 72 f16 = 144 B (16B-aligned)
    __shared__ __align__(16) _Float16 hbuf0[16][72];
    __shared__ __align__(16) _Float16 hbuf1[16][72];

    // this wave's K=32 weight frags for its single M-tile (mt = w)
    const f16x8* wf8 = (const f16x8*)wfrags;
    f16x8 w0[2], wx[2], wh[2];
#pragma unroll
    for (int kf = 0; kf < 2; ++kf) {
        w0[kf] = wf8[(w * 2 + kf) * 64 + l];        // Wh0
        wx[kf] = wf8[(8 + w * 2 + kf) * 64 + l];    // Wx1
        wh[kf] = wf8[(16 + w * 2 + kf) * 64 + l];   // Wh1
    }

    const f32x4 b1v = ((const f32x4*)b1)[w * 4 + q];

    // hidden state as K=32 B-frags (full 64 units each, held by every wave)
    f16x8 h0f0, h0f1, h1f0, h1f1;
#pragma unroll
    for (int j = 0; j < 8; ++j) {
        h0f0[j] = (_Float16)0.0f; h0f1[j] = (_Float16)0.0f;
        h1f0[j] = (_Float16)0.0f; h1f1[j] = (_Float16)0.0f;
    }

    const f32x4* embWv = (const f32x4*)embW;
    const int tokbase = (row0 + r) * SEQ;

    // embW slots for t=0..3 (period-4 in-place pipeline)
    int4 tk0 = *(const int4*)&tokens[tokbase];
    int4 tk  = *(const int4*)&tokens[tokbase + 4];   // window: t+4..t+7
    f32x4 e0 = embWv[tk0.x * 16 + w * 4 + q];
    f32x4 e1 = embWv[tk0.y * 16 + w * 4 + q];
    f32x4 e2 = embWv[tk0.z * 16 + w * 4 + q];
    f32x4 e3 = embWv[tk0.w * 16 + w * 4 + q];

    for (int k = 0; k < SEQ / 4; ++k) {
        // token window for t+8..t+11 (clamped tail: feeds only dead loads)
        int off = (4 * k + 8 <= SEQ - 4) ? (4 * k + 8) : (SEQ - 4);
        int4 tkC = *(const int4*)&tokens[tokbase + off];

        RNN_STEP(e0, tk.x)   // t = 4k
        RNN_STEP(e1, tk.y)   // t = 4k+1
        RNN_STEP(e2, tk.z)   // t = 4k+2
        RNN_STEP(e3, tk.w)   // t = 4k+3

        tk = tkC;
    }

    // ---- output head: out[row] = sigmoid(h1 . Wout + bout) ----
    // h1f0[j] = h1[r][8q+j], h1f1[j] = h1[r][32+8q+j]; every wave holds the
    // full state, wave 0 stores.
    if (w == 0) {
        f32x4 wo0 = ((const f32x4*)Wout)[2 * q];
        f32x4 wo1 = ((const f32x4*)Wout)[2 * q + 1];
        f32x4 wo2 = ((const f32x4*)Wout)[8 + 2 * q];
        f32x4 wo3 = ((const f32x4*)Wout)[8 + 2 * q + 1];
        float accv = 0.0f;
#pragma unroll
        for (int j = 0; j < 4; ++j) {
            accv = fmaf((float)h1f0[j],     wo0[j], accv);
            accv = fmaf((float)h1f0[4 + j], wo1[j], accv);
            accv = fmaf((float)h1f1[j],     wo2[j], accv);
            accv = fmaf((float)h1f1[4 + j], wo3[j], accv);
        }
        accv += __shfl_down(accv, 16);
        accv += __shfl_down(accv, 32);
        if (l < 16) {
            float z = accv + bout[0];
            out[row0 + r] = 1.0f / (1.0f + __expf(-z));
        }
    }
}

extern "C" void kernel_launch(void* const* d_in, const int* in_sizes, int n_in,
                              void* d_out, int out_size, void* d_ws, size_t ws_size,
                              hipStream_t stream) {
    const int*   tokens = (const int*)d_in[0];
    const float* emb    = (const float*)d_in[1];
    const float* Wx0    = (const float*)d_in[2];
    const float* Wh0    = (const float*)d_in[3];
    const float* b0     = (const float*)d_in[4];
    const float* Wx1    = (const float*)d_in[5];
    const float* Wh1    = (const float*)d_in[6];
    const float* b1     = (const float*)d_in[7];
    const float* Wout   = (const float*)d_in[8];
    const float* bout   = (const float*)d_in[9];
    float* out = (float*)d_out;

    // ws layout: embW fp32 (2,560,000 B) | packed f16 weight frags (24,576 B)
    float* embW = (float*)d_ws;
    _Float16* wfrags =
        (_Float16*)((char*)d_ws + (size_t)TOTAL_WORDS * UNITS * 4);

    prep_kernel<<<298, 256, 0, stream>>>(emb, Wx0, b0, Wh0, Wx1, Wh1,
                                         embW, wfrags);
    rnn_mfma_kernel<<<BATCH / 16, 256, 0, stream>>>(tokens, embW, wfrags,
                                                    b1, Wout, bout, out);
}

// Round 2
// 130.784 us; speedup vs baseline: 1.0233x; 1.0233x over previous
//
#include <hip/hip_runtime.h>

// Problem constants (from reference)
#define TOTAL_WORDS 10000
#define EMB 100
#define SEQ 80
#define UNITS 64
#define BATCH 16384

// ---------------------------------------------------------------------------
// R16: barrier-free recurrence via unit-permutation. R15 post-mortem showed
// the bottleneck is the per-step critical path (MFMA->tanh->LDS->barrier->
// LDS->MFMA), not occupancy: independent chains/CU = blocks/CU = 4 (fixed),
// and intra-block waves are barrier-locked.
// Fix: one wave = full 64-unit state for 16 batch rows. Permute the unit
// ordering of the A-frag M-rows (prep packing), embW C-init, and b1 by
//   kappa(t, 4g+s) = 32*(t>>1) + 8*g + 4*(t&1) + s
// so the MFMA C-output (lane n+16g, tile t, reg s) IS the element the next
// step's B-frag needs in that same lane/slot:
//   h0f0 = cat(tanh_pack(a0), tanh_pack(a1)); h0f1 = cat(tp(a2), tp(a3)).
// -> zero LDS, zero barriers, zero cross-lane ops in the 80-step loop.
// Accumulation order per output unit is unchanged -> absmax identical.
// prep_kernel: only the frag-pack col formula changes (kappa instead of
// mt*16+mm); embW stays natural order.
// ---------------------------------------------------------------------------

typedef _Float16 f16x4 __attribute__((ext_vector_type(4)));
typedef _Float16 f16x8 __attribute__((ext_vector_type(8)));
typedef _Float16 h2    __attribute__((ext_vector_type(2)));
typedef __fp16   fp16x2r __attribute__((ext_vector_type(2)));  // cvt_pkrtz ret
typedef float    f32x4 __attribute__((ext_vector_type(4)));

__device__ __forceinline__ h2 pkcvt(float a, float b) {
    fp16x2r t = __builtin_amdgcn_cvt_pkrtz(a, b);
    h2 o; o[0] = (_Float16)t[0]; o[1] = (_Float16)t[1];
    return o;
}

__device__ __forceinline__ h2 tanh_h2(h2 x) {
    // odd deg-5 in packed f16: |x| <= ~0.3 -> added err ~2e-4
    const _Float16 c3 = (_Float16)(-0.33333333f);
    const _Float16 c5 = (_Float16)(0.13333333f);
    h2 x2 = x * x;
    h2 p  = x2 * c5 + c3;     // v_pk_fma_f16
    h2 x3 = x2 * x;
    return x3 * p + x;        // v_pk_fma_f16
}

__device__ __forceinline__ f16x4 tanh_pack(f32x4 a) {
    h2 lo = tanh_h2(pkcvt(a[0], a[1]));
    h2 hi = tanh_h2(pkcvt(a[2], a[3]));
    f16x4 o;
    o[0] = lo[0]; o[1] = lo[1]; o[2] = hi[0]; o[3] = hi[1];
    return o;
}

__device__ __forceinline__ f16x8 cat8(f16x4 a, f16x4 b) {
    f16x8 o;
    o[0] = a[0]; o[1] = a[1]; o[2] = a[2]; o[3] = a[3];
    o[4] = b[0]; o[5] = b[1]; o[6] = b[2]; o[7] = b[3];
    return o;
}

// ------------------- fused prologue: embW + weight packing -----------------
// blocks [0,250): embW rows [b*40, b*40+40), natural unit order (unchanged).
// blocks [250,298): pack K=32 A-frags for Wh0 / Wx1 / Wh1. M-rows permuted:
//   frag (mat, f=mt*2+kf) elem (lane l, j) = W[kf*32+(l>>4)*8+j][kappa(mt,mm)]
//   with mm = l&15, kappa = 32*(mt>>1) + 8*(mm>>2) + 4*(mt&1) + (mm&3).
__global__ void prep_kernel(const float* __restrict__ emb,
                            const float* __restrict__ Wx0,
                            const float* __restrict__ b0,
                            const float* __restrict__ Wh0,
                            const float* __restrict__ Wx1,
                            const float* __restrict__ Wh1,
                            float* __restrict__ embW,
                            _Float16* __restrict__ wfrags) {
    int b = blockIdx.x;
    if (b < 250) {
        __shared__ float wx[EMB * UNITS];  // 25.6 KB
        for (int i = threadIdx.x; i < EMB * UNITS; i += 256)
            wx[i] = Wx0[i];
        __syncthreads();
        const int u = threadIdx.x & 63;
        const int wvi = threadIdx.x >> 6;            // wave-uniform
        const int vbase = b * 40 + wvi * 10;         // wave-uniform
        const float bias = b0[u];
        float acc[10];
#pragma unroll
        for (int i = 0; i < 10; ++i) acc[i] = bias;
        const float* er = emb + vbase * EMB;         // wave-uniform base
#pragma unroll 4
        for (int k = 0; k < EMB; ++k) {
            float wxv = wx[k * UNITS + u];
#pragma unroll
            for (int i = 0; i < 10; ++i)
                acc[i] = fmaf(er[i * EMB + k], wxv, acc[i]);
        }
#pragma unroll
        for (int i = 0; i < 10; ++i)
            embW[(vbase + i) * UNITS + u] = acc[i];
    } else {
        int e = (b - 250) * 256 + threadIdx.x;       // 0..12287
        int mat = e >> 12;                           // 0: Wh0, 1: Wx1, 2: Wh1
        int ee = e & 4095;
        int f = ee >> 9;                             // frag 0..7
        int mt = f >> 1, kf = f & 1;
        int rr = ee & 511;
        int l = rr >> 3, j = rr & 7;
        int k = kf * 32 + (l >> 4) * 8 + j;
        int mm = l & 15;
        // permuted output-unit label: kappa(mt, mm)
        int col = 32 * (mt >> 1) + 8 * (mm >> 2) + 4 * (mt & 1) + (mm & 3);
        const float* W = (mat == 0) ? Wh0 : (mat == 1) ? Wx1 : Wh1;
        wfrags[e] = (_Float16)W[k * UNITS + col];
    }
}

// ------------------------------ main kernel --------------------------------
// One wave (64 threads) owns 16 batch rows and the full 64-unit state.
// Lane l: q = l>>4 (k-slice group), n = l&15 (batch row).
// Per step: 24 MFMAs (8 layer-0, 16 layer-1), tanh+pack in-lane, no LDS.
// E: f32x4[4] embW slots for this step (consumed as layer-0 C-init,
// reloaded for t+4). T4: token at t+4.
// embW v-index for tile t: tok*16 + EOFS(t) + 2q, EOFS = {0,1,8,9}.
#define MF(A, B, C) __builtin_amdgcn_mfma_f32_16x16x32_f16(A, B, C, 0, 0, 0)
#define EOFS(t) (8 * ((t) >> 1) + ((t) & 1))

#define RNN_STEP(E, T4)                                                       \
    {                                                                         \
        f32x4 a0 = E[0], a1 = E[1], a2 = E[2], a3 = E[3];                     \
        a0 = MF(w0[0][0], h0f0, a0); a1 = MF(w0[1][0], h0f0, a1);             \
        a2 = MF(w0[2][0], h0f0, a2); a3 = MF(w0[3][0], h0f0, a3);             \
        a0 = MF(w0[0][1], h0f1, a0); a1 = MF(w0[1][1], h0f1, a1);             \
        a2 = MF(w0[2][1], h0f1, a2); a3 = MF(w0[3][1], h0f1, a3);             \
        E[0] = embWv[(T4) * 16 + EOFS(0) + 2 * q];   /* reload for t+4 */     \
        E[1] = embWv[(T4) * 16 + EOFS(1) + 2 * q];                            \
        E[2] = embWv[(T4) * 16 + EOFS(2) + 2 * q];                            \
        E[3] = embWv[(T4) * 16 + EOFS(3) + 2 * q];                            \
        f32x4 c0 = b1v[0], c1 = b1v[1], c2 = b1v[2], c3 = b1v[3];             \
        c0 = MF(wh[0][0], h1f0, c0); c1 = MF(wh[1][0], h1f0, c1);             \
        c2 = MF(wh[2][0], h1f0, c2); c3 = MF(wh[3][0], h1f0, c3);             \
        c0 = MF(wh[0][1], h1f1, c0); c1 = MF(wh[1][1], h1f1, c1);             \
        c2 = MF(wh[2][1], h1f1, c2); c3 = MF(wh[3][1], h1f1, c3);             \
        h0f0 = cat8(tanh_pack(a0), tanh_pack(a1));                            \
        h0f1 = cat8(tanh_pack(a2), tanh_pack(a3));                            \
        c0 = MF(wx[0][0], h0f0, c0); c1 = MF(wx[1][0], h0f0, c1);             \
        c2 = MF(wx[2][0], h0f0, c2); c3 = MF(wx[3][0], h0f0, c3);             \
        c0 = MF(wx[0][1], h0f1, c0); c1 = MF(wx[1][1], h0f1, c1);             \
        c2 = MF(wx[2][1], h0f1, c2); c3 = MF(wx[3][1], h0f1, c3);             \
        h1f0 = cat8(tanh_pack(c0), tanh_pack(c1));                            \
        h1f1 = cat8(tanh_pack(c2), tanh_pack(c3));                            \
    }

__global__ __launch_bounds__(64, 1) void rnn_mfma_kernel(
    const int*      __restrict__ tokens,   // [BATCH][SEQ]
    const float*    __restrict__ embW,     // [TOTAL_WORDS][UNITS]
    const _Float16* __restrict__ wfrags,   // packed f16 K=32 A-frags
    const float*    __restrict__ b1,       // [UNITS]
    const float*    __restrict__ Wout,     // [UNITS]
    const float*    __restrict__ bout,     // [1]
    float*          __restrict__ out) {    // [BATCH]
    const int l = threadIdx.x;     // 0..63 (one wave per block)
    const int q = l >> 4;          // k-slice group 0..3
    const int n = l & 15;          // batch row within the block's 16-row group
    const int row0 = blockIdx.x * 16;

    // full weight set for all 4 M-tiles (96 VGPRs)
    const f16x8* wf8 = (const f16x8*)wfrags;
    f16x8 w0[4][2], wx[4][2], wh[4][2];
#pragma unroll
    for (int t = 0; t < 4; ++t)
#pragma unroll
        for (int kf = 0; kf < 2; ++kf) {
            w0[t][kf] = wf8[(t * 2 + kf) * 64 + l];        // Wh0
            wx[t][kf] = wf8[(8 + t * 2 + kf) * 64 + l];    // Wx1
            wh[t][kf] = wf8[(16 + t * 2 + kf) * 64 + l];   // Wh1
        }

    // layer-1 bias in permuted (kappa) order: same index formula as embW
    const f32x4* b1v4 = (const f32x4*)b1;
    f32x4 b1v[4];
#pragma unroll
    for (int t = 0; t < 4; ++t)
        b1v[t] = b1v4[EOFS(t) + 2 * q];

    // hidden state as K=32 B-frags (natural unit order on the K axis)
    f16x8 h0f0, h0f1, h1f0, h1f1;
#pragma unroll
    for (int j = 0; j < 8; ++j) {
        h0f0[j] = (_Float16)0.0f; h0f1[j] = (_Float16)0.0f;
        h1f0[j] = (_Float16)0.0f; h1f1[j] = (_Float16)0.0f;
    }

    const f32x4* embWv = (const f32x4*)embW;
    const int tokbase = (row0 + n) * SEQ;

    // embW slots for t=0..3 (period-4 in-place pipeline)
    int4 tk0 = *(const int4*)&tokens[tokbase];
    int4 tk  = *(const int4*)&tokens[tokbase + 4];   // window: t+4..t+7
    f32x4 e0[4], e1[4], e2[4], e3[4];
#pragma unroll
    for (int t = 0; t < 4; ++t) {
        e0[t] = embWv[tk0.x * 16 + EOFS(t) + 2 * q];
        e1[t] = embWv[tk0.y * 16 + EOFS(t) + 2 * q];
        e2[t] = embWv[tk0.z * 16 + EOFS(t) + 2 * q];
        e3[t] = embWv[tk0.w * 16 + EOFS(t) + 2 * q];
    }

    for (int k = 0; k < SEQ / 4; ++k) {
        // token window for t+8..t+11 (clamped tail: feeds only dead loads)
        int off = (4 * k + 8 <= SEQ - 4) ? (4 * k + 8) : (SEQ - 4);
        int4 tkC = *(const int4*)&tokens[tokbase + off];

        RNN_STEP(e0, tk.x)   // t = 4k
        RNN_STEP(e1, tk.y)   // t = 4k+1
        RNN_STEP(e2, tk.z)   // t = 4k+2
        RNN_STEP(e3, tk.w)   // t = 4k+3

        tk = tkC;
    }

    // ---- output head: out[row] = sigmoid(h1 . Wout + bout) ----
    // h1f0[j] = h1[n][8q+j], h1f1[j] = h1[n][32+8q+j] (natural unit order).
    // Reduce the 4 q-groups via shfl, lanes 0..15 store.
    {
        f32x4 wo0 = ((const f32x4*)Wout)[2 * q];
        f32x4 wo1 = ((const f32x4*)Wout)[2 * q + 1];
        f32x4 wo2 = ((const f32x4*)Wout)[8 + 2 * q];
        f32x4 wo3 = ((const f32x4*)Wout)[8 + 2 * q + 1];
        float accv = 0.0f;
#pragma unroll
        for (int j = 0; j < 4; ++j) {
            accv = fmaf((float)h1f0[j],     wo0[j], accv);
            accv = fmaf((float)h1f0[4 + j], wo1[j], accv);
            accv = fmaf((float)h1f1[j],     wo2[j], accv);
            accv = fmaf((float)h1f1[4 + j], wo3[j], accv);
        }
        accv += __shfl_down(accv, 16);
        accv += __shfl_down(accv, 32);
        if (l < 16) {
            float z = accv + bout[0];
            out[row0 + n] = 1.0f / (1.0f + __expf(-z));
        }
    }
}

extern "C" void kernel_launch(void* const* d_in, const int* in_sizes, int n_in,
                              void* d_out, int out_size, void* d_ws, size_t ws_size,
                              hipStream_t stream) {
    const int*   tokens = (const int*)d_in[0];
    const float* emb    = (const float*)d_in[1];
    const float* Wx0    = (const float*)d_in[2];
    const float* Wh0    = (const float*)d_in[3];
    const float* b0     = (const float*)d_in[4];
    const float* Wx1    = (const float*)d_in[5];
    const float* Wh1    = (const float*)d_in[6];
    const float* b1     = (const float*)d_in[7];
    const float* Wout   = (const float*)d_in[8];
    const float* bout   = (const float*)d_in[9];
    float* out = (float*)d_out;

    // ws layout: embW fp32 (2,560,000 B) | packed f16 weight frags (24,576 B)
    float* embW = (float*)d_ws;
    _Float16* wfrags =
        (_Float16*)((char*)d_ws + (size_t)TOTAL_WORDS * UNITS * 4);

    prep_kernel<<<298, 256, 0, stream>>>(emb, Wx0, b0, Wh0, Wx1, Wh1,
                                         embW, wfrags);
    rnn_mfma_kernel<<<BATCH / 16, 64, 0, stream>>>(tokens, embW, wfrags,
                                                   b1, Wout, bout, out);
}